// Round 7
// baseline (2291.164 us; speedup 1.0000x reference)
//
#include <hip/hip_runtime.h>
#include <math.h>

// B=4, S=1024, D=1024, H=16, DK=64.  NTOK = B*S.
#define NTOK 4096
typedef unsigned int uint;

// head-split layout: [B,H,S,DK], elem = ((b*16+h)<<16) + (s<<6) + dk
__device__ __forceinline__ int split_idx(int n, int d) {
  int b = n >> 10, s = n & 1023, h = d >> 6, dk = d & 63;
  return (((b << 4) + h) << 16) + (s << 6) + dk;
}

__device__ __forceinline__ ushort bf16_rne(float f) {
  uint u = __float_as_uint(f);
  return (ushort)((u + 0x7FFFu + ((u >> 16) & 1u)) >> 16);
}
__device__ __forceinline__ float bf16f(ushort h) {
  return __uint_as_float(((uint)h) << 16);
}

typedef __attribute__((ext_vector_type(8))) short bf16x8;
typedef __attribute__((ext_vector_type(4))) float f32x4;

__device__ __forceinline__ void gload16(const void* g, void* l) {
  __builtin_amdgcn_global_load_lds(
      (const __attribute__((address_space(1))) void*)g,
      (__attribute__((address_space(3))) void*)l, 16, 0, 0);
}

// ---------------------------------------------------------------------------
// fp32 -> (bf16 hi, bf16 lo) split conversion.  z = tensor id.
// ---------------------------------------------------------------------------
struct ConvP {
  const float4* s[14];
  ushort* hi[14];
  ushort* lo[14];
  int n4[14];
};
__global__ __launch_bounds__(256) void convert_split(ConvP C) {
  const int z = blockIdx.z;
  const int id = blockIdx.x * 256 + threadIdx.x;
  if (id >= C.n4[z]) return;
  const float4 x = C.s[z][id];
  const float xs[4] = {x.x, x.y, x.z, x.w};
  ushort hs[4], ls[4];
#pragma unroll
  for (int k = 0; k < 4; ++k) {
    hs[k] = bf16_rne(xs[k]);
    ls[k] = bf16_rne(xs[k] - bf16f(hs[k]));  // exact residual
  }
  ushort4 hv; hv.x = hs[0]; hv.y = hs[1]; hv.z = hs[2]; hv.w = hs[3];
  ushort4 lv; lv.x = ls[0]; lv.y = ls[1]; lv.z = ls[2]; lv.w = ls[3];
  *(ushort4*)&C.hi[z][id * 4] = hv;
  *(ushort4*)&C.lo[z][id * 4] = lv;
}

// ---------------------------------------------------------------------------
// Split-bf16 MFMA GEMM (unchanged; passed rounds 2 and 6).
// ---------------------------------------------------------------------------
struct MG {
  const char* ah[6]; const char* al[6];
  const char* bh[6]; const char* bl[6];
  const float* bias[6]; float* y[6];
};

template<bool SPLIT_IN, bool SPLIT_OUT>
__global__ __launch_bounds__(256, 3) void gemm_mfma(MG P) {
  __shared__ ushort sAhi[4096], sAlo[4096], sBhi[4096], sBlo[4096];
  const int z = blockIdx.z;
  const char* __restrict__ Ah = P.ah[z];
  const char* __restrict__ Al = P.al[z];
  const char* __restrict__ Bh = P.bh[z];
  const char* __restrict__ Bl = P.bl[z];

  const int t = threadIdx.x, l = t & 63, w = t >> 6;
  const int wm = w >> 1, wn = w & 1;
  const int bn0 = blockIdx.x * 128, bm0 = blockIdx.y * 128;

  int offA[2], offB[2];
  {
    const int srow = w * 16 + (l >> 2), scd = l & 3;
#pragma unroll
    for (int q = 0; q < 2; ++q) {
      const int r = srow + q * 64;
      const int cc = scd ^ ((r >> 1) & 3);
      const int m = bm0 + r, n = bn0 + r;
      offA[q] = SPLIT_IN
                    ? ((((m >> 10) << 20) + ((m & 1023) << 6) + cc * 8) * 2)
                    : (m * 2048 + cc * 16);
      offB[q] = n * 2048 + cc * 16;
    }
  }
  int aoff[4], boff[4];
  {
    const int frow = l & 15, fc = l >> 4;
#pragma unroll
    for (int f = 0; f < 4; ++f) {
      const int ra = wm * 64 + f * 16 + frow;
      aoff[f] = ra * 64 + ((fc ^ ((ra >> 1) & 3)) * 16);
      const int rb = wn * 64 + f * 16 + frow;
      boff[f] = rb * 64 + ((fc ^ ((rb >> 1) & 3)) * 16);
    }
  }

  f32x4 acc[4][4];
#pragma unroll
  for (int i = 0; i < 4; ++i)
#pragma unroll
    for (int j = 0; j < 4; ++j) acc[i][j] = (f32x4){0.f, 0.f, 0.f, 0.f};

  for (int k0 = 0; k0 < 1024; k0 += 32) {
    __syncthreads();
    const int scA = SPLIT_IN ? ((((k0 >> 6) << 16) + (k0 & 63)) * 2) : (k0 * 2);
    const int scB = k0 * 2;
    gload16(Ah + offA[0] + scA, (char*)sAhi + w * 1024);
    gload16(Ah + offA[1] + scA, (char*)sAhi + 4096 + w * 1024);
    gload16(Al + offA[0] + scA, (char*)sAlo + w * 1024);
    gload16(Al + offA[1] + scA, (char*)sAlo + 4096 + w * 1024);
    gload16(Bh + offB[0] + scB, (char*)sBhi + w * 1024);
    gload16(Bh + offB[1] + scB, (char*)sBhi + 4096 + w * 1024);
    gload16(Bl + offB[0] + scB, (char*)sBlo + w * 1024);
    gload16(Bl + offB[1] + scB, (char*)sBlo + 4096 + w * 1024);
    __syncthreads();

    bf16x8 fah[4], fal[4], fbh[4], fbl[4];
#pragma unroll
    for (int f = 0; f < 4; ++f) {
      fah[f] = *(const bf16x8*)((const char*)sAhi + aoff[f]);
      fal[f] = *(const bf16x8*)((const char*)sAlo + aoff[f]);
      fbh[f] = *(const bf16x8*)((const char*)sBhi + boff[f]);
      fbl[f] = *(const bf16x8*)((const char*)sBlo + boff[f]);
    }
#pragma unroll
    for (int fi = 0; fi < 4; ++fi)
#pragma unroll
      for (int fj = 0; fj < 4; ++fj) {
        acc[fi][fj] = __builtin_amdgcn_mfma_f32_16x16x32_bf16(
            fah[fi], fbh[fj], acc[fi][fj], 0, 0, 0);
        acc[fi][fj] = __builtin_amdgcn_mfma_f32_16x16x32_bf16(
            fah[fi], fbl[fj], acc[fi][fj], 0, 0, 0);
        acc[fi][fj] = __builtin_amdgcn_mfma_f32_16x16x32_bf16(
            fal[fi], fbh[fj], acc[fi][fj], 0, 0, 0);
      }
  }

  const float* __restrict__ bias = P.bias[z];
  float* __restrict__ Y = P.y[z];
  float bv[4];
#pragma unroll
  for (int fj = 0; fj < 4; ++fj)
    bv[fj] = bias[bn0 + wn * 64 + fj * 16 + (l & 15)];
#pragma unroll
  for (int fi = 0; fi < 4; ++fi)
#pragma unroll
    for (int fj = 0; fj < 4; ++fj) {
      const int n = bn0 + wn * 64 + fj * 16 + (l & 15);
#pragma unroll
      for (int r = 0; r < 4; ++r) {
        const int m = bm0 + wm * 64 + fi * 16 + (l >> 4) * 4 + r;
        const float val = acc[fi][fj][r] + bv[fj];
        if constexpr (SPLIT_OUT) Y[split_idx(m, n)] = val;
        else Y[m * 1024 + n] = val;
      }
    }
}

// ---------------------------------------------------------------------------
// fp32 GEMM fallback (small-ws path).
// ---------------------------------------------------------------------------
struct GemmPtrs {
  const float* x[6]; const float* w[6]; const float* b[6]; float* y[6];
};
template<bool SPLIT_IN, bool SPLIT_OUT>
__global__ __launch_bounds__(256, 4) void gemm_kernel(GemmPtrs P) {
  const int z = blockIdx.z;
  const float* __restrict__ A = P.x[z];
  const float* __restrict__ W = P.w[z];
  const float* __restrict__ bias = P.b[z];
  float* __restrict__ Y = P.y[z];
  __shared__ float As[16][132];
  __shared__ float Bs[16][132];
  const int t = threadIdx.x;
  const int tx = t & 15, ty = t >> 4;
  const int bm0 = blockIdx.y * 128, bn0 = blockIdx.x * 128;
  float acc[8][8];
#pragma unroll
  for (int ii = 0; ii < 8; ++ii)
#pragma unroll
    for (int jj = 0; jj < 8; ++jj) acc[ii][jj] = 0.f;
  for (int k0 = 0; k0 < 1024; k0 += 16) {
    float4 av[2], bv[2];
#pragma unroll
    for (int q = 0; q < 2; ++q) {
      const int f = q * 256 + t, row = f >> 2, k4 = f & 3, gk = k0 + k4 * 4;
      if constexpr (SPLIT_IN) av[q] = *(const float4*)&A[split_idx(bm0 + row, gk)];
      else av[q] = *(const float4*)&A[(bm0 + row) * 1024 + gk];
      bv[q] = *(const float4*)&W[(bn0 + row) * 1024 + gk];
    }
    __syncthreads();
#pragma unroll
    for (int q = 0; q < 2; ++q) {
      const int f = q * 256 + t, row = f >> 2, k4 = f & 3;
      As[k4 * 4 + 0][row] = av[q].x; As[k4 * 4 + 1][row] = av[q].y;
      As[k4 * 4 + 2][row] = av[q].z; As[k4 * 4 + 3][row] = av[q].w;
      Bs[k4 * 4 + 0][row] = bv[q].x; Bs[k4 * 4 + 1][row] = bv[q].y;
      Bs[k4 * 4 + 2][row] = bv[q].z; Bs[k4 * 4 + 3][row] = bv[q].w;
    }
    __syncthreads();
#pragma unroll
    for (int k = 0; k < 16; ++k) {
      const float4 a0 = *(const float4*)&As[k][ty * 4];
      const float4 a1 = *(const float4*)&As[k][64 + ty * 4];
      const float4 b0 = *(const float4*)&Bs[k][tx * 4];
      const float4 b1 = *(const float4*)&Bs[k][64 + tx * 4];
      const float am[8] = {a0.x, a0.y, a0.z, a0.w, a1.x, a1.y, a1.z, a1.w};
      const float bn[8] = {b0.x, b0.y, b0.z, b0.w, b1.x, b1.y, b1.z, b1.w};
#pragma unroll
      for (int ii = 0; ii < 8; ++ii)
#pragma unroll
        for (int jj = 0; jj < 8; ++jj)
          acc[ii][jj] = fmaf(am[ii], bn[jj], acc[ii][jj]);
    }
  }
  const float4 bia0 = *(const float4*)&bias[bn0 + tx * 4];
  const float4 bia1 = *(const float4*)&bias[bn0 + 64 + tx * 4];
  const float bb[8] = {bia0.x, bia0.y, bia0.z, bia0.w,
                       bia1.x, bia1.y, bia1.z, bia1.w};
#pragma unroll
  for (int ii = 0; ii < 8; ++ii) {
    const int m = bm0 + ((ii < 4) ? (ty * 4 + ii) : (64 + ty * 4 + ii - 4));
    float4 r0, r1;
    r0.x = acc[ii][0] + bb[0]; r0.y = acc[ii][1] + bb[1];
    r0.z = acc[ii][2] + bb[2]; r0.w = acc[ii][3] + bb[3];
    r1.x = acc[ii][4] + bb[4]; r1.y = acc[ii][5] + bb[5];
    r1.z = acc[ii][6] + bb[6]; r1.w = acc[ii][7] + bb[7];
    if constexpr (SPLIT_OUT) {
      *(float4*)&Y[split_idx(m, bn0 + tx * 4)] = r0;
      *(float4*)&Y[split_idx(m, bn0 + 64 + tx * 4)] = r1;
    } else {
      *(float4*)&Y[m * 1024 + bn0 + tx * 4] = r0;
      *(float4*)&Y[m * 1024 + bn0 + 64 + tx * 4] = r1;
    }
  }
}

// ---------------------------------------------------------------------------
// Fused decay attention, v3b.
// IDENTICAL to round-6 v3 except __launch_bounds__(512, 2):
// round 6 measured VGPR_Count=64 + WRITE_SIZE=942MB -> the (512,4) bound
// (min 4 waves/EU => VGPR cap 512/4=128) forced v[8][16] (~200 VGPR demand)
// into scratch.  Cap 256 lets scores live in registers; expected 1 block/CU
// (8 waves), compensated by 8-way ILP per wave.
// ---------------------------------------------------------------------------
__device__ __forceinline__ float wmax64(float x) {
#pragma unroll
  for (int off = 32; off > 0; off >>= 1) x = fmaxf(x, __shfl_xor(x, off));
  return x;
}
__device__ __forceinline__ float wsum64(float x) {
#pragma unroll
  for (int off = 32; off > 0; off >>= 1) x += __shfl_xor(x, off);
  return x;
}

template<bool BF16OUT>
__global__ __launch_bounds__(512, 2) void decay_attn3(
    const float* __restrict__ qm, const float* __restrict__ km,
    const float* __restrict__ vm, const float* __restrict__ qc,
    const float* __restrict__ kc, const float* __restrict__ vc,
    float* __restrict__ om, float* __restrict__ oc,
    ushort* __restrict__ omh, ushort* __restrict__ oml,
    ushort* __restrict__ och, ushort* __restrict__ ocl,
    const float* __restrict__ gammas) {
  __shared__ __align__(16) char kvraw[2][16384];  // K/V chunk double-buffer
  __shared__ float q_s[64][64];                   // block's q rows (broadcast)
  __shared__ float p_s[8][8][64];                 // per-wave p chunk for PV

  const int t = threadIdx.x, l = t & 63, w = t >> 6;
  const int bh = blockIdx.y, h = bh & 15;
  const int q0 = blockIdx.x * 64;
  const int nchunks = blockIdx.x + 1;  // chunks of 64 keys
  const int path = blockIdx.z;
  const int base = bh << 16;
  const float* Q = (path ? qc : qm) + base;
  const float* K = (path ? kc : km) + base;
  const float* V = (path ? vc : vm) + base;
  const float g = -log1pf(__expf(gammas[h]));

  // stage q rows (natural layout; reads are wave-uniform broadcasts)
#pragma unroll
  for (int qq = 0; qq < 2; ++qq) {
    const int f = qq * 512 + t, row = f >> 4, c4 = f & 15;
    *(float4*)&q_s[row][c4 * 4] = *(const float4*)&Q[(q0 + row) * 64 + c4 * 4];
  }
  // stage K chunk 0 (pre-swizzled source, linear LDS dest)
#pragma unroll
  for (int qq = 0; qq < 2; ++qq) {
    const int f = qq * 512 + t, j = f >> 4, cc = f & 15;
    gload16((const char*)K + (j << 8) + ((cc ^ (j & 7)) << 4),
            &kvraw[0][0] + qq * 8192 + w * 1024);
  }
  __syncthreads();

  float v[8][16];  // scores, STATIC indexing only

  // ---- phase 1: scores (lane = j within chunk; K row in regs via b128) ----
#pragma unroll
  for (int c = 0; c < 16; ++c) {
    if (c < nchunks) {
      if (c + 1 < nchunks) {
        const char* Ksrc = (const char*)K + (((c + 1) << 6) << 8);
#pragma unroll
        for (int qq = 0; qq < 2; ++qq) {
          const int f = qq * 512 + t, j = f >> 4, cc = f & 15;
          gload16(Ksrc + (j << 8) + ((cc ^ (j & 7)) << 4),
                  &kvraw[(c + 1) & 1][0] + qq * 8192 + w * 1024);
        }
      }
      const char* kb = &kvraw[c & 1][0];
      float2 d2[8];
#pragma unroll
      for (int rr = 0; rr < 8; ++rr) d2[rr] = make_float2(0.f, 0.f);
#pragma unroll
      for (int g4 = 0; g4 < 4; ++g4) {
        float4 kr[4];
#pragma unroll
        for (int u = 0; u < 4; ++u) {
          const int c4 = g4 * 4 + u;
          kr[u] = *(const float4*)(kb + l * 256 + ((c4 ^ (l & 7)) << 4));
        }
#pragma unroll
        for (int rr = 0; rr < 8; ++rr) {
#pragma unroll
          for (int u = 0; u < 4; ++u) {
            const float4 q4 = *(const float4*)&q_s[w * 8 + rr][(g4 * 4 + u) * 4];
            d2[rr] += make_float2(q4.x, q4.y) * make_float2(kr[u].x, kr[u].y)
                    + make_float2(q4.z, q4.w) * make_float2(kr[u].z, kr[u].w);
          }
        }
      }
#pragma unroll
      for (int rr = 0; rr < 8; ++rr)
        v[rr][c] = (d2[rr].x + d2[rr].y) * 0.125f;  // 1/sqrt(64)
      __syncthreads();
    }
  }

  // stage V chunk 0 now (overlaps with phase 2; drained by the next barrier)
#pragma unroll
  for (int qq = 0; qq < 2; ++qq) {
    const int f = qq * 512 + t, j = f >> 4, cc = f & 15;
    gload16((const char*)V + (j << 8) + ((cc ^ (j & 7)) << 4),
            &kvraw[0][0] + qq * 8192 + w * 1024);
  }

  // ---- phase 2: decay softmax per row (registers + shfl) ----
#pragma unroll
  for (int rr = 0; rr < 8; ++rr) {
    const int i = q0 + w * 8 + rr;
    float m1 = -INFINITY;
#pragma unroll
    for (int tt = 0; tt < 16; ++tt)
      if (tt < nchunks) {
        const int j = tt * 64 + l;
        m1 = fmaxf(m1, (j <= i) ? v[rr][tt] : -INFINITY);
      }
    m1 = wmax64(m1);

    float x[16], T[16];
    float zl = 0.f;
#pragma unroll
    for (int tt = 0; tt < 16; ++tt)
      if (tt < nchunks) {
        const int j = tt * 64 + l;
        x[tt] = (j <= i) ? __expf(v[rr][tt] - m1) : 0.f;
        zl += x[tt];
      }
    const float rz1 = 1.f / wsum64(zl);

    // unnormalized inclusive scans; rz1 folded into the decay exponent
#pragma unroll
    for (int tt = 0; tt < 16; ++tt)
      if (tt < nchunks) {
#pragma unroll
        for (int off = 1; off < 64; off <<= 1) {
          const float nb = __shfl_up(x[tt], off);
          if (l >= off) x[tt] += nb;
        }
        T[tt] = __shfl(x[tt], 63);
      }
    float tot = 0.f;
#pragma unroll
    for (int tt = 0; tt < 16; ++tt)
      if (tt < nchunks) tot += T[tt];

    const float gs = g * sqrtf(rz1);
    float run = 0.f, m2 = -INFINITY;
#pragma unroll
    for (int tt = 0; tt < 16; ++tt)
      if (tt < nchunks) {
        const int j = tt * 64 + l;
        const float cum = run + x[tt];
        run += T[tt];
        const float dist = sqrtf(fmaxf((tot - cum) * (float)(i - j), 0.f));
        float eff = __expf(gs * dist);
        eff = fminf(fmaxf(eff, 1e-5f), 1e5f);
        const float s2 = (j <= i) ? v[rr][tt] * eff : -INFINITY;
        v[rr][tt] = s2;
        m2 = fmaxf(m2, s2);
      }
    m2 = wmax64(m2);

    float z2 = 0.f;
#pragma unroll
    for (int tt = 0; tt < 16; ++tt)
      if (tt < nchunks) {
        const float e2 = __expf(v[rr][tt] - m2);
        v[rr][tt] = e2;
        z2 += e2;
      }
    const float rz2 = 1.f / wsum64(z2);
#pragma unroll
    for (int tt = 0; tt < 16; ++tt)
      if (tt < nchunks) v[rr][tt] *= rz2;
  }
  __syncthreads();  // V chunk 0 staged + all waves done with phase 2

  // ---- phase 3: PV (lane = output dim d) ----
  float2 acc2[8];
#pragma unroll
  for (int rr = 0; rr < 8; ++rr) acc2[rr] = make_float2(0.f, 0.f);
#pragma unroll
  for (int c = 0; c < 16; ++c) {
    if (c < nchunks) {
      if (c + 1 < nchunks) {
        const char* Vsrc = (const char*)V + (((c + 1) << 6) << 8);
#pragma unroll
        for (int qq = 0; qq < 2; ++qq) {
          const int f = qq * 512 + t, j = f >> 4, cc = f & 15;
          gload16(Vsrc + (j << 8) + ((cc ^ (j & 7)) << 4),
                  &kvraw[(c + 1) & 1][0] + qq * 8192 + w * 1024);
        }
      }
      const char* vb = &kvraw[c & 1][0];
#pragma unroll
      for (int rr = 0; rr < 8; ++rr) p_s[w][rr][l] = v[rr][c];
#pragma unroll
      for (int j4 = 0; j4 < 16; ++j4) {
        float vj[4];
#pragma unroll
        for (int u = 0; u < 4; ++u) {
          const int j = j4 * 4 + u;
          vj[u] = *(const float*)(vb + (j << 8) +
                                  ((((l >> 2) ^ (j & 7))) << 4) + ((l & 3) << 2));
        }
#pragma unroll
        for (int rr = 0; rr < 8; ++rr) {
          const float4 p4 = *(const float4*)&p_s[w][rr][j4 * 4];  // broadcast
          acc2[rr] += make_float2(p4.x, p4.y) * make_float2(vj[0], vj[1])
                    + make_float2(p4.z, p4.w) * make_float2(vj[2], vj[3]);
        }
      }
      __syncthreads();
    }
  }

#pragma unroll
  for (int rr = 0; rr < 8; ++rr) {
    const int i = q0 + w * 8 + rr;
    const int idx = base + i * 64 + l;
    const float a = acc2[rr].x + acc2[rr].y;
    if constexpr (BF16OUT) {
      const ushort hb = bf16_rne(a);
      const ushort lb = bf16_rne(a - bf16f(hb));
      (path ? och : omh)[idx] = hb;
      (path ? ocl : oml)[idx] = lb;
    } else {
      (path ? oc : om)[idx] = a;
    }
  }
}

// ---------------------------------------------------------------------------
extern "C" void kernel_launch(void* const* d_in, const int* in_sizes, int n_in,
                              void* d_out, int out_size, void* d_ws,
                              size_t ws_size, hipStream_t stream) {
  (void)in_sizes; (void)n_in; (void)out_size;

  const float* X[6];
  for (int i = 0; i < 6; ++i) X[i] = (const float*)d_in[i];
  const float* Wt[8]; const float* Bs[8];
  for (int i = 0; i < 8; ++i) {
    Wt[i] = (const float*)d_in[7 + 2 * i];
    Bs[i] = (const float*)d_in[8 + 2 * i];
  }
  const float* gam = (const float*)d_in[23];
  float* out_mean = (float*)d_out;
  float* out_cov = out_mean + (size_t)NTOK * 1024;

  const size_t MB = 1024ull * 1024ull;
  const size_t NEED = 224ull * MB;
  char* ws = (char*)d_ws;

  if (ws_size >= NEED) {
    ushort* Xhi = (ushort*)(ws + 0);          // 6 x 8MB
    ushort* Xlo = (ushort*)(ws + 48 * MB);    // 6 x 8MB
    ushort* Whi = (ushort*)(ws + 96 * MB);    // 8 x 2MB
    ushort* Wlo = (ushort*)(ws + 112 * MB);   // 8 x 2MB
    float* QKV = (float*)(ws + 128 * MB);     // 6 x 16MB head-split fp32
    ushort* OMh = (ushort*)(ws + 0 * MB);     // alias X region (consumed)
    ushort* OMl = (ushort*)(ws + 8 * MB);
    ushort* OCh = (ushort*)(ws + 16 * MB);
    ushort* OCl = (ushort*)(ws + 24 * MB);

    const size_t XE = 4194304, WE = 1048576, QE = 4194304;

    ConvP C = {};
    for (int i = 0; i < 6; ++i) {
      C.s[i] = (const float4*)X[i];
      C.hi[i] = Xhi + (size_t)i * XE;
      C.lo[i] = Xlo + (size_t)i * XE;
      C.n4[i] = (int)(XE / 4);
    }
    for (int i = 0; i < 8; ++i) {
      C.s[6 + i] = (const float4*)Wt[i];
      C.hi[6 + i] = Whi + (size_t)i * WE;
      C.lo[6 + i] = Wlo + (size_t)i * WE;
      C.n4[6 + i] = (int)(WE / 4);
    }
    convert_split<<<dim3(4096, 1, 14), 256, 0, stream>>>(C);

    MG Pin = {};
    for (int z = 0; z < 6; ++z) {
      Pin.ah[z] = (const char*)(Xhi + (size_t)z * XE);
      Pin.al[z] = (const char*)(Xlo + (size_t)z * XE);
      Pin.bh[z] = (const char*)(Whi + (size_t)z * WE);
      Pin.bl[z] = (const char*)(Wlo + (size_t)z * WE);
      Pin.bias[z] = Bs[z];
      Pin.y[z] = QKV + (size_t)z * QE;
    }
    gemm_mfma<false, true><<<dim3(8, 32, 6), 256, 0, stream>>>(Pin);

    float* qm = QKV + 0 * QE; float* qc = QKV + 1 * QE;
    float* km = QKV + 2 * QE; float* kc = QKV + 3 * QE;
    float* vm = QKV + 4 * QE; float* vc = QKV + 5 * QE;
    decay_attn3<true><<<dim3(16, 64, 2), 512, 0, stream>>>(
        qm, km, vm, qc, kc, vc, nullptr, nullptr, OMh, OMl, OCh, OCl, gam);

    MG Pout = {};
    Pout.ah[0] = (const char*)OMh; Pout.al[0] = (const char*)OMl;
    Pout.bh[0] = (const char*)(Whi + 6 * WE);
    Pout.bl[0] = (const char*)(Wlo + 6 * WE);
    Pout.bias[0] = Bs[6]; Pout.y[0] = out_mean;
    Pout.ah[1] = (const char*)OCh; Pout.al[1] = (const char*)OCl;
    Pout.bh[1] = (const char*)(Whi + 7 * WE);
    Pout.bl[1] = (const char*)(Wlo + 7 * WE);
    Pout.bias[1] = Bs[7]; Pout.y[1] = out_cov;
    gemm_mfma<true, false><<<dim3(8, 32, 2), 256, 0, stream>>>(Pout);
  } else {
    float* qkv = (float*)ws;                  // 6 x 16MB
    float* om = (float*)(ws + 96 * MB);
    float* ocv = (float*)(ws + 112 * MB);
    const size_t QE = 4194304;

    GemmPtrs Pin = {};
    for (int z = 0; z < 6; ++z) {
      Pin.x[z] = X[z]; Pin.w[z] = Wt[z]; Pin.b[z] = Bs[z];
      Pin.y[z] = qkv + (size_t)z * QE;
    }
    gemm_kernel<false, true><<<dim3(8, 32, 6), 256, 0, stream>>>(Pin);

    decay_attn3<false><<<dim3(16, 64, 2), 512, 0, stream>>>(
        qkv + 0 * QE, qkv + 2 * QE, qkv + 4 * QE, qkv + 1 * QE, qkv + 3 * QE,
        qkv + 5 * QE, om, ocv, nullptr, nullptr, nullptr, nullptr, gam);

    GemmPtrs Pout = {};
    Pout.x[0] = om; Pout.w[0] = Wt[6]; Pout.b[0] = Bs[6]; Pout.y[0] = out_mean;
    Pout.x[1] = ocv; Pout.w[1] = Wt[7]; Pout.b[1] = Bs[7]; Pout.y[1] = out_cov;
    gemm_kernel<true, false><<<dim3(8, 32, 2), 256, 0, stream>>>(Pout);
  }
}

// Round 8
// 1806.425 us; speedup vs baseline: 1.2683x; 1.2683x over previous
//
#include <hip/hip_runtime.h>
#include <math.h>

// B=4, S=1024, D=1024, H=16, DK=64.  NTOK = B*S.
#define NTOK 4096
typedef unsigned int uint;

// head-split layout: [B,H,S,DK], elem = ((b*16+h)<<16) + (s<<6) + dk
__device__ __forceinline__ int split_idx(int n, int d) {
  int b = n >> 10, s = n & 1023, h = d >> 6, dk = d & 63;
  return (((b << 4) + h) << 16) + (s << 6) + dk;
}

__device__ __forceinline__ ushort bf16_rne(float f) {
  uint u = __float_as_uint(f);
  return (ushort)((u + 0x7FFFu + ((u >> 16) & 1u)) >> 16);
}
__device__ __forceinline__ float bf16f(ushort h) {
  return __uint_as_float(((uint)h) << 16);
}

typedef __attribute__((ext_vector_type(8))) short bf16x8;
typedef __attribute__((ext_vector_type(4))) float f32x4;

__device__ __forceinline__ void gload16(const void* g, void* l) {
  __builtin_amdgcn_global_load_lds(
      (const __attribute__((address_space(1))) void*)g,
      (__attribute__((address_space(3))) void*)l, 16, 0, 0);
}

// ---------------------------------------------------------------------------
// fp32 -> (bf16 hi, bf16 lo) split conversion.  z = tensor id.
// ---------------------------------------------------------------------------
struct ConvP {
  const float4* s[14];
  ushort* hi[14];
  ushort* lo[14];
  int n4[14];
};
__global__ __launch_bounds__(256) void convert_split(ConvP C) {
  const int z = blockIdx.z;
  const int id = blockIdx.x * 256 + threadIdx.x;
  if (id >= C.n4[z]) return;
  const float4 x = C.s[z][id];
  const float xs[4] = {x.x, x.y, x.z, x.w};
  ushort hs[4], ls[4];
#pragma unroll
  for (int k = 0; k < 4; ++k) {
    hs[k] = bf16_rne(xs[k]);
    ls[k] = bf16_rne(xs[k] - bf16f(hs[k]));  // exact residual
  }
  ushort4 hv; hv.x = hs[0]; hv.y = hs[1]; hv.z = hs[2]; hv.w = hs[3];
  ushort4 lv; lv.x = ls[0]; lv.y = ls[1]; lv.z = ls[2]; lv.w = ls[3];
  *(ushort4*)&C.hi[z][id * 4] = hv;
  *(ushort4*)&C.lo[z][id * 4] = lv;
}

// ---------------------------------------------------------------------------
// Split-bf16 MFMA GEMM (unchanged; passed rounds 2, 6, 7).
// ---------------------------------------------------------------------------
struct MG {
  const char* ah[6]; const char* al[6];
  const char* bh[6]; const char* bl[6];
  const float* bias[6]; float* y[6];
};

template<bool SPLIT_IN, bool SPLIT_OUT>
__global__ __launch_bounds__(256, 3) void gemm_mfma(MG P) {
  __shared__ ushort sAhi[4096], sAlo[4096], sBhi[4096], sBlo[4096];
  const int z = blockIdx.z;
  const char* __restrict__ Ah = P.ah[z];
  const char* __restrict__ Al = P.al[z];
  const char* __restrict__ Bh = P.bh[z];
  const char* __restrict__ Bl = P.bl[z];

  const int t = threadIdx.x, l = t & 63, w = t >> 6;
  const int wm = w >> 1, wn = w & 1;
  const int bn0 = blockIdx.x * 128, bm0 = blockIdx.y * 128;

  int offA[2], offB[2];
  {
    const int srow = w * 16 + (l >> 2), scd = l & 3;
#pragma unroll
    for (int q = 0; q < 2; ++q) {
      const int r = srow + q * 64;
      const int cc = scd ^ ((r >> 1) & 3);
      const int m = bm0 + r, n = bn0 + r;
      offA[q] = SPLIT_IN
                    ? ((((m >> 10) << 20) + ((m & 1023) << 6) + cc * 8) * 2)
                    : (m * 2048 + cc * 16);
      offB[q] = n * 2048 + cc * 16;
    }
  }
  int aoff[4], boff[4];
  {
    const int frow = l & 15, fc = l >> 4;
#pragma unroll
    for (int f = 0; f < 4; ++f) {
      const int ra = wm * 64 + f * 16 + frow;
      aoff[f] = ra * 64 + ((fc ^ ((ra >> 1) & 3)) * 16);
      const int rb = wn * 64 + f * 16 + frow;
      boff[f] = rb * 64 + ((fc ^ ((rb >> 1) & 3)) * 16);
    }
  }

  f32x4 acc[4][4];
#pragma unroll
  for (int i = 0; i < 4; ++i)
#pragma unroll
    for (int j = 0; j < 4; ++j) acc[i][j] = (f32x4){0.f, 0.f, 0.f, 0.f};

  for (int k0 = 0; k0 < 1024; k0 += 32) {
    __syncthreads();
    const int scA = SPLIT_IN ? ((((k0 >> 6) << 16) + (k0 & 63)) * 2) : (k0 * 2);
    const int scB = k0 * 2;
    gload16(Ah + offA[0] + scA, (char*)sAhi + w * 1024);
    gload16(Ah + offA[1] + scA, (char*)sAhi + 4096 + w * 1024);
    gload16(Al + offA[0] + scA, (char*)sAlo + w * 1024);
    gload16(Al + offA[1] + scA, (char*)sAlo + 4096 + w * 1024);
    gload16(Bh + offB[0] + scB, (char*)sBhi + w * 1024);
    gload16(Bh + offB[1] + scB, (char*)sBhi + 4096 + w * 1024);
    gload16(Bl + offB[0] + scB, (char*)sBlo + w * 1024);
    gload16(Bl + offB[1] + scB, (char*)sBlo + 4096 + w * 1024);
    __syncthreads();

    bf16x8 fah[4], fal[4], fbh[4], fbl[4];
#pragma unroll
    for (int f = 0; f < 4; ++f) {
      fah[f] = *(const bf16x8*)((const char*)sAhi + aoff[f]);
      fal[f] = *(const bf16x8*)((const char*)sAlo + aoff[f]);
      fbh[f] = *(const bf16x8*)((const char*)sBhi + boff[f]);
      fbl[f] = *(const bf16x8*)((const char*)sBlo + boff[f]);
    }
#pragma unroll
    for (int fi = 0; fi < 4; ++fi)
#pragma unroll
      for (int fj = 0; fj < 4; ++fj) {
        acc[fi][fj] = __builtin_amdgcn_mfma_f32_16x16x32_bf16(
            fah[fi], fbh[fj], acc[fi][fj], 0, 0, 0);
        acc[fi][fj] = __builtin_amdgcn_mfma_f32_16x16x32_bf16(
            fah[fi], fbl[fj], acc[fi][fj], 0, 0, 0);
        acc[fi][fj] = __builtin_amdgcn_mfma_f32_16x16x32_bf16(
            fal[fi], fbh[fj], acc[fi][fj], 0, 0, 0);
      }
  }

  const float* __restrict__ bias = P.bias[z];
  float* __restrict__ Y = P.y[z];
  float bv[4];
#pragma unroll
  for (int fj = 0; fj < 4; ++fj)
    bv[fj] = bias[bn0 + wn * 64 + fj * 16 + (l & 15)];
#pragma unroll
  for (int fi = 0; fi < 4; ++fi)
#pragma unroll
    for (int fj = 0; fj < 4; ++fj) {
      const int n = bn0 + wn * 64 + fj * 16 + (l & 15);
#pragma unroll
      for (int r = 0; r < 4; ++r) {
        const int m = bm0 + wm * 64 + fi * 16 + (l >> 4) * 4 + r;
        const float val = acc[fi][fj][r] + bv[fj];
        if constexpr (SPLIT_OUT) Y[split_idx(m, n)] = val;
        else Y[m * 1024 + n] = val;
      }
    }
}

// ---------------------------------------------------------------------------
// fp32 GEMM fallback (small-ws path).
// ---------------------------------------------------------------------------
struct GemmPtrs {
  const float* x[6]; const float* w[6]; const float* b[6]; float* y[6];
};
template<bool SPLIT_IN, bool SPLIT_OUT>
__global__ __launch_bounds__(256, 4) void gemm_kernel(GemmPtrs P) {
  const int z = blockIdx.z;
  const float* __restrict__ A = P.x[z];
  const float* __restrict__ W = P.w[z];
  const float* __restrict__ bias = P.b[z];
  float* __restrict__ Y = P.y[z];
  __shared__ float As[16][132];
  __shared__ float Bs[16][132];
  const int t = threadIdx.x;
  const int tx = t & 15, ty = t >> 4;
  const int bm0 = blockIdx.y * 128, bn0 = blockIdx.x * 128;
  float acc[8][8];
#pragma unroll
  for (int ii = 0; ii < 8; ++ii)
#pragma unroll
    for (int jj = 0; jj < 8; ++jj) acc[ii][jj] = 0.f;
  for (int k0 = 0; k0 < 1024; k0 += 16) {
    float4 av[2], bv[2];
#pragma unroll
    for (int q = 0; q < 2; ++q) {
      const int f = q * 256 + t, row = f >> 2, k4 = f & 3, gk = k0 + k4 * 4;
      if constexpr (SPLIT_IN) av[q] = *(const float4*)&A[split_idx(bm0 + row, gk)];
      else av[q] = *(const float4*)&A[(bm0 + row) * 1024 + gk];
      bv[q] = *(const float4*)&W[(bn0 + row) * 1024 + gk];
    }
    __syncthreads();
#pragma unroll
    for (int q = 0; q < 2; ++q) {
      const int f = q * 256 + t, row = f >> 2, k4 = f & 3;
      As[k4 * 4 + 0][row] = av[q].x; As[k4 * 4 + 1][row] = av[q].y;
      As[k4 * 4 + 2][row] = av[q].z; As[k4 * 4 + 3][row] = av[q].w;
      Bs[k4 * 4 + 0][row] = bv[q].x; Bs[k4 * 4 + 1][row] = bv[q].y;
      Bs[k4 * 4 + 2][row] = bv[q].z; Bs[k4 * 4 + 3][row] = bv[q].w;
    }
    __syncthreads();
#pragma unroll
    for (int k = 0; k < 16; ++k) {
      const float4 a0 = *(const float4*)&As[k][ty * 4];
      const float4 a1 = *(const float4*)&As[k][64 + ty * 4];
      const float4 b0 = *(const float4*)&Bs[k][tx * 4];
      const float4 b1 = *(const float4*)&Bs[k][64 + tx * 4];
      const float am[8] = {a0.x, a0.y, a0.z, a0.w, a1.x, a1.y, a1.z, a1.w};
      const float bn[8] = {b0.x, b0.y, b0.z, b0.w, b1.x, b1.y, b1.z, b1.w};
#pragma unroll
      for (int ii = 0; ii < 8; ++ii)
#pragma unroll
        for (int jj = 0; jj < 8; ++jj)
          acc[ii][jj] = fmaf(am[ii], bn[jj], acc[ii][jj]);
    }
  }
  const float4 bia0 = *(const float4*)&bias[bn0 + tx * 4];
  const float4 bia1 = *(const float4*)&bias[bn0 + 64 + tx * 4];
  const float bb[8] = {bia0.x, bia0.y, bia0.z, bia0.w,
                       bia1.x, bia1.y, bia1.z, bia1.w};
#pragma unroll
  for (int ii = 0; ii < 8; ++ii) {
    const int m = bm0 + ((ii < 4) ? (ty * 4 + ii) : (64 + ty * 4 + ii - 4));
    float4 r0, r1;
    r0.x = acc[ii][0] + bb[0]; r0.y = acc[ii][1] + bb[1];
    r0.z = acc[ii][2] + bb[2]; r0.w = acc[ii][3] + bb[3];
    r1.x = acc[ii][4] + bb[4]; r1.y = acc[ii][5] + bb[5];
    r1.z = acc[ii][6] + bb[6]; r1.w = acc[ii][7] + bb[7];
    if constexpr (SPLIT_OUT) {
      *(float4*)&Y[split_idx(m, bn0 + tx * 4)] = r0;
      *(float4*)&Y[split_idx(m, bn0 + 64 + tx * 4)] = r1;
    } else {
      *(float4*)&Y[m * 1024 + bn0 + tx * 4] = r0;
      *(float4*)&Y[m * 1024 + bn0 + 64 + tx * 4] = r1;
    }
  }
}

// ---------------------------------------------------------------------------
// Fused decay attention, v4.
// Round-7 lesson: 8 rows/lane of scores (v[8][16]=128 VGPR) + scan temps can
// NEVER fit the 128-VGPR cap that 64KB-LDS occupancy implies -> permanent
// spill (WRITE_SIZE 662-942 MB).  v4 halves per-thread state instead:
// block = 1024 thr = 16 waves, wave owns 4 rows -> v[4][16] = 64 VGPR.
// T[16] eliminated (chunk totals re-read via __shfl(x,63)).  Per-row softmax
// is an inlined function called 4x with STATIC v[0..3] refs (rule #20).
// Peak demand ~110 < 128 cap.  QT=64 kept -> same K/V traffic as round 7.
// ---------------------------------------------------------------------------
__device__ __forceinline__ float wmax64(float x) {
#pragma unroll
  for (int off = 32; off > 0; off >>= 1) x = fmaxf(x, __shfl_xor(x, off));
  return x;
}
__device__ __forceinline__ float wsum64(float x) {
#pragma unroll
  for (int off = 32; off > 0; off >>= 1) x += __shfl_xor(x, off);
  return x;
}

// Decay softmax over one row held as vr[16] (j = tt*64 + l), in place.
__device__ __forceinline__ void softmax_row(float (&vr)[16], const int i,
                                            const int nchunks, const float g,
                                            const int l) {
  float m1 = -INFINITY;
#pragma unroll
  for (int tt = 0; tt < 16; ++tt)
    if (tt < nchunks) {
      const int j = tt * 64 + l;
      m1 = fmaxf(m1, (j <= i) ? vr[tt] : -INFINITY);
    }
  m1 = wmax64(m1);

  float x[16];
  float zl = 0.f;
#pragma unroll
  for (int tt = 0; tt < 16; ++tt)
    if (tt < nchunks) {
      const int j = tt * 64 + l;
      x[tt] = (j <= i) ? __expf(vr[tt] - m1) : 0.f;
      zl += x[tt];
    }
  const float rz1 = 1.f / wsum64(zl);

  // unnormalized inclusive scan per chunk (independent -> ILP)
#pragma unroll
  for (int tt = 0; tt < 16; ++tt)
    if (tt < nchunks) {
#pragma unroll
      for (int off = 1; off < 64; off <<= 1) {
        const float nb = __shfl_up(x[tt], off);
        if (l >= off) x[tt] += nb;
      }
    }
  float tot = 0.f;
#pragma unroll
  for (int tt = 0; tt < 16; ++tt)
    if (tt < nchunks) tot += __shfl(x[tt], 63);

  const float gs = g * sqrtf(rz1);  // folds the 1/z1 normalization into g
  float run = 0.f, m2 = -INFINITY;
#pragma unroll
  for (int tt = 0; tt < 16; ++tt)
    if (tt < nchunks) {
      const int j = tt * 64 + l;
      const float cum = run + x[tt];
      run += __shfl(x[tt], 63);
      const float dist = sqrtf(fmaxf((tot - cum) * (float)(i - j), 0.f));
      float eff = __expf(gs * dist);
      eff = fminf(fmaxf(eff, 1e-5f), 1e5f);
      const float s2 = (j <= i) ? vr[tt] * eff : -INFINITY;
      vr[tt] = s2;
      m2 = fmaxf(m2, s2);
    }
  m2 = wmax64(m2);

  float z2 = 0.f;
#pragma unroll
  for (int tt = 0; tt < 16; ++tt)
    if (tt < nchunks) {
      const float e2 = __expf(vr[tt] - m2);
      vr[tt] = e2;
      z2 += e2;
    }
  const float rz2 = 1.f / wsum64(z2);
#pragma unroll
  for (int tt = 0; tt < 16; ++tt)
    if (tt < nchunks) vr[tt] *= rz2;
}

template<bool BF16OUT>
__global__ __launch_bounds__(1024, 1) void decay_attn4(
    const float* __restrict__ qm, const float* __restrict__ km,
    const float* __restrict__ vm, const float* __restrict__ qc,
    const float* __restrict__ kc, const float* __restrict__ vc,
    float* __restrict__ om, float* __restrict__ oc,
    ushort* __restrict__ omh, ushort* __restrict__ oml,
    ushort* __restrict__ och, ushort* __restrict__ ocl,
    const float* __restrict__ gammas) {
  __shared__ __align__(16) char kvraw[2][16384];  // K/V chunk double-buffer
  __shared__ float q_s[64][64];                   // block's q rows (broadcast)
  __shared__ float p_s[16][4][64];                // per-wave p chunk for PV

  const int t = threadIdx.x, l = t & 63, w = t >> 6;  // w in 0..15
  const int bh = blockIdx.y, h = bh & 15;
  const int q0 = blockIdx.x * 64;
  const int nchunks = blockIdx.x + 1;  // chunks of 64 keys
  const int path = blockIdx.z;
  const int base = bh << 16;
  const float* Q = (path ? qc : qm) + base;
  const float* K = (path ? kc : km) + base;
  const float* V = (path ? vc : vm) + base;
  const float g = -log1pf(__expf(gammas[h]));

  // stage q rows: one float4 per thread (natural layout; reads broadcast)
  {
    const int row = t >> 4, c4 = t & 15;
    *(float4*)&q_s[row][c4 * 4] = *(const float4*)&Q[(q0 + row) * 64 + c4 * 4];
  }
  // stage K chunk 0 (pre-swizzled source, linear LDS dest; 16B/thread)
  {
    const int j = t >> 4, cc = t & 15;
    gload16((const char*)K + (j << 8) + ((cc ^ (j & 7)) << 4),
            &kvraw[0][0] + w * 1024);
  }
  __syncthreads();

  float v[4][16];  // scores: 64 VGPR, STATIC indexing only

  // ---- phase 1: scores (lane = j within chunk; K rows via ds_read_b128) ----
#pragma unroll
  for (int c = 0; c < 16; ++c) {
    if (c < nchunks) {
      if (c + 1 < nchunks) {
        const char* Ksrc = (const char*)K + (((c + 1) << 6) << 8);
        const int j = t >> 4, cc = t & 15;
        gload16(Ksrc + (j << 8) + ((cc ^ (j & 7)) << 4),
                &kvraw[(c + 1) & 1][0] + w * 1024);
      }
      const char* kb = &kvraw[c & 1][0];
      float2 d2[4];
#pragma unroll
      for (int rr = 0; rr < 4; ++rr) d2[rr] = make_float2(0.f, 0.f);
#pragma unroll
      for (int g4 = 0; g4 < 4; ++g4) {
        float4 kr[4];
#pragma unroll
        for (int u = 0; u < 4; ++u) {
          const int c4 = g4 * 4 + u;
          kr[u] = *(const float4*)(kb + l * 256 + ((c4 ^ (l & 7)) << 4));
        }
#pragma unroll
        for (int rr = 0; rr < 4; ++rr) {
#pragma unroll
          for (int u = 0; u < 4; ++u) {
            const float4 q4 = *(const float4*)&q_s[w * 4 + rr][(g4 * 4 + u) * 4];
            d2[rr] += make_float2(q4.x, q4.y) * make_float2(kr[u].x, kr[u].y)
                    + make_float2(q4.z, q4.w) * make_float2(kr[u].z, kr[u].w);
          }
        }
      }
#pragma unroll
      for (int rr = 0; rr < 4; ++rr)
        v[rr][c] = (d2[rr].x + d2[rr].y) * 0.125f;  // 1/sqrt(64)
      __syncthreads();
    }
  }

  // stage V chunk 0 (overlaps register-only phase 2; drained by next barrier)
  {
    const int j = t >> 4, cc = t & 15;
    gload16((const char*)V + (j << 8) + ((cc ^ (j & 7)) << 4),
            &kvraw[0][0] + w * 1024);
  }

  // ---- phase 2: decay softmax, 4 rows, static calls ----
  softmax_row(v[0], q0 + w * 4 + 0, nchunks, g, l);
  softmax_row(v[1], q0 + w * 4 + 1, nchunks, g, l);
  softmax_row(v[2], q0 + w * 4 + 2, nchunks, g, l);
  softmax_row(v[3], q0 + w * 4 + 3, nchunks, g, l);
  __syncthreads();  // V chunk 0 staged + all waves done with phase 2

  // ---- phase 3: PV (lane = output dim d) ----
  float2 acc2[4];
#pragma unroll
  for (int rr = 0; rr < 4; ++rr) acc2[rr] = make_float2(0.f, 0.f);
#pragma unroll
  for (int c = 0; c < 16; ++c) {
    if (c < nchunks) {
      if (c + 1 < nchunks) {
        const char* Vsrc = (const char*)V + (((c + 1) << 6) << 8);
        const int j = t >> 4, cc = t & 15;
        gload16(Vsrc + (j << 8) + ((cc ^ (j & 7)) << 4),
                &kvraw[(c + 1) & 1][0] + w * 1024);
      }
      const char* vb = &kvraw[c & 1][0];
#pragma unroll
      for (int rr = 0; rr < 4; ++rr) p_s[w][rr][l] = v[rr][c];
#pragma unroll
      for (int j4 = 0; j4 < 16; ++j4) {
        float vj[4];
#pragma unroll
        for (int u = 0; u < 4; ++u) {
          const int j = j4 * 4 + u;
          vj[u] = *(const float*)(vb + (j << 8) +
                                  ((((l >> 2) ^ (j & 7))) << 4) + ((l & 3) << 2));
        }
#pragma unroll
        for (int rr = 0; rr < 4; ++rr) {
          const float4 p4 = *(const float4*)&p_s[w][rr][j4 * 4];  // broadcast
          acc2[rr] += make_float2(p4.x, p4.y) * make_float2(vj[0], vj[1])
                    + make_float2(p4.z, p4.w) * make_float2(vj[2], vj[3]);
        }
      }
      __syncthreads();
    }
  }

#pragma unroll
  for (int rr = 0; rr < 4; ++rr) {
    const int i = q0 + w * 4 + rr;
    const int idx = base + i * 64 + l;
    const float a = acc2[rr].x + acc2[rr].y;
    if constexpr (BF16OUT) {
      const ushort hb = bf16_rne(a);
      const ushort lb = bf16_rne(a - bf16f(hb));
      (path ? och : omh)[idx] = hb;
      (path ? ocl : oml)[idx] = lb;
    } else {
      (path ? oc : om)[idx] = a;
    }
  }
}

// ---------------------------------------------------------------------------
extern "C" void kernel_launch(void* const* d_in, const int* in_sizes, int n_in,
                              void* d_out, int out_size, void* d_ws,
                              size_t ws_size, hipStream_t stream) {
  (void)in_sizes; (void)n_in; (void)out_size;

  const float* X[6];
  for (int i = 0; i < 6; ++i) X[i] = (const float*)d_in[i];
  const float* Wt[8]; const float* Bs[8];
  for (int i = 0; i < 8; ++i) {
    Wt[i] = (const float*)d_in[7 + 2 * i];
    Bs[i] = (const float*)d_in[8 + 2 * i];
  }
  const float* gam = (const float*)d_in[23];
  float* out_mean = (float*)d_out;
  float* out_cov = out_mean + (size_t)NTOK * 1024;

  const size_t MB = 1024ull * 1024ull;
  const size_t NEED = 224ull * MB;
  char* ws = (char*)d_ws;

  if (ws_size >= NEED) {
    ushort* Xhi = (ushort*)(ws + 0);          // 6 x 8MB
    ushort* Xlo = (ushort*)(ws + 48 * MB);    // 6 x 8MB
    ushort* Whi = (ushort*)(ws + 96 * MB);    // 8 x 2MB
    ushort* Wlo = (ushort*)(ws + 112 * MB);   // 8 x 2MB
    float* QKV = (float*)(ws + 128 * MB);     // 6 x 16MB head-split fp32
    ushort* OMh = (ushort*)(ws + 0 * MB);     // alias X region (consumed)
    ushort* OMl = (ushort*)(ws + 8 * MB);
    ushort* OCh = (ushort*)(ws + 16 * MB);
    ushort* OCl = (ushort*)(ws + 24 * MB);

    const size_t XE = 4194304, WE = 1048576, QE = 4194304;

    ConvP C = {};
    for (int i = 0; i < 6; ++i) {
      C.s[i] = (const float4*)X[i];
      C.hi[i] = Xhi + (size_t)i * XE;
      C.lo[i] = Xlo + (size_t)i * XE;
      C.n4[i] = (int)(XE / 4);
    }
    for (int i = 0; i < 8; ++i) {
      C.s[6 + i] = (const float4*)Wt[i];
      C.hi[6 + i] = Whi + (size_t)i * WE;
      C.lo[6 + i] = Wlo + (size_t)i * WE;
      C.n4[6 + i] = (int)(WE / 4);
    }
    convert_split<<<dim3(4096, 1, 14), 256, 0, stream>>>(C);

    MG Pin = {};
    for (int z = 0; z < 6; ++z) {
      Pin.ah[z] = (const char*)(Xhi + (size_t)z * XE);
      Pin.al[z] = (const char*)(Xlo + (size_t)z * XE);
      Pin.bh[z] = (const char*)(Whi + (size_t)z * WE);
      Pin.bl[z] = (const char*)(Wlo + (size_t)z * WE);
      Pin.bias[z] = Bs[z];
      Pin.y[z] = QKV + (size_t)z * QE;
    }
    gemm_mfma<false, true><<<dim3(8, 32, 6), 256, 0, stream>>>(Pin);

    float* qm = QKV + 0 * QE; float* qc = QKV + 1 * QE;
    float* km = QKV + 2 * QE; float* kc = QKV + 3 * QE;
    float* vm = QKV + 4 * QE; float* vc = QKV + 5 * QE;
    decay_attn4<true><<<dim3(16, 64, 2), 1024, 0, stream>>>(
        qm, km, vm, qc, kc, vc, nullptr, nullptr, OMh, OMl, OCh, OCl, gam);

    MG Pout = {};
    Pout.ah[0] = (const char*)OMh; Pout.al[0] = (const char*)OMl;
    Pout.bh[0] = (const char*)(Whi + 6 * WE);
    Pout.bl[0] = (const char*)(Wlo + 6 * WE);
    Pout.bias[0] = Bs[6]; Pout.y[0] = out_mean;
    Pout.ah[1] = (const char*)OCh; Pout.al[1] = (const char*)OCl;
    Pout.bh[1] = (const char*)(Whi + 7 * WE);
    Pout.bl[1] = (const char*)(Wlo + 7 * WE);
    Pout.bias[1] = Bs[7]; Pout.y[1] = out_cov;
    gemm_mfma<true, false><<<dim3(8, 32, 2), 256, 0, stream>>>(Pout);
  } else {
    float* qkv = (float*)ws;                  // 6 x 16MB
    float* om = (float*)(ws + 96 * MB);
    float* ocv = (float*)(ws + 112 * MB);
    const size_t QE = 4194304;

    GemmPtrs Pin = {};
    for (int z = 0; z < 6; ++z) {
      Pin.x[z] = X[z]; Pin.w[z] = Wt[z]; Pin.b[z] = Bs[z];
      Pin.y[z] = qkv + (size_t)z * QE;
    }
    gemm_kernel<false, true><<<dim3(8, 32, 6), 256, 0, stream>>>(Pin);

    decay_attn4<false><<<dim3(16, 64, 2), 1024, 0, stream>>>(
        qkv + 0 * QE, qkv + 2 * QE, qkv + 4 * QE, qkv + 1 * QE, qkv + 3 * QE,
        qkv + 5 * QE, om, ocv, nullptr, nullptr, nullptr, nullptr, gam);

    GemmPtrs Pout = {};
    Pout.x[0] = om; Pout.w[0] = Wt[6]; Pout.b[0] = Bs[6]; Pout.y[0] = out_mean;
    Pout.x[1] = ocv; Pout.w[1] = Wt[7]; Pout.b[1] = Bs[7]; Pout.y[1] = out_cov;
    gemm_kernel<true, false><<<dim3(8, 32, 2), 256, 0, stream>>>(Pout);
  }
}